// Round 1
// baseline (540.271 us; speedup 1.0000x reference)
//
#include <hip/hip_runtime.h>
#include <hip/hip_bf16.h>

#define B_ 8
#define N_ 4096
#define D_ 1024

// ---------------------------------------------------------------------------
// K1: q16[r][d] = l2norm(layernorm(phi[r]*qg+qb)) for the 16 core slot rows.
// One wave per row.
// ---------------------------------------------------------------------------
__global__ __launch_bounds__(64) void k_q16(
    const float* __restrict__ phi, const float* __restrict__ qg, const float* __restrict__ qb,
    const float* __restrict__ lng, const float* __restrict__ lnb, float* __restrict__ q16)
{
    int r = blockIdx.x;        // 0..15  (= e*2+s, e<8)
    int lane = threadIdx.x;    // 0..63
    const float* pr = phi + (size_t)r * D_;
    float v[16];
    float s1 = 0.f;
#pragma unroll
    for (int c = 0; c < 16; ++c) {
        int i = c * 64 + lane;
        v[c] = pr[i] * qg[i] + qb[i];
        s1 += v[c];
    }
#pragma unroll
    for (int m = 32; m; m >>= 1) s1 += __shfl_xor(s1, m);
    float mu = s1 * (1.0f / D_);
    float s2 = 0.f;
#pragma unroll
    for (int c = 0; c < 16; ++c) { float dd = v[c] - mu; s2 += dd * dd; }
#pragma unroll
    for (int m = 32; m; m >>= 1) s2 += __shfl_xor(s2, m);
    float var = s2 * (1.0f / D_);
    float inv = 1.0f / sqrtf(var + 1e-5f);
    float u[16];
    float s3 = 0.f;
#pragma unroll
    for (int c = 0; c < 16; ++c) {
        int i = c * 64 + lane;
        u[c] = (v[c] - mu) * inv * lng[i] + lnb[i];
        s3 += u[c] * u[c];
    }
#pragma unroll
    for (int m = 32; m; m >>= 1) s3 += __shfl_xor(s3, m);
    float rn = 1.0f / (sqrtf(s3) + 1e-6f);
#pragma unroll
    for (int c = 0; c < 16; ++c) q16[(size_t)r * D_ + c * 64 + lane] = u[c] * rn;
}

// ---------------------------------------------------------------------------
// K2a: per-token routing. k = l2norm(x*kg+kb); logits = k . q16[j];
// dispatch = 8-way softmax per slot; combine = 16-way entmax15.
// One wave per token (8 tokens per wave sequentially). q16 staged in LDS.
// ---------------------------------------------------------------------------
__global__ __launch_bounds__(256) void k_route(
    const float* __restrict__ x, const float* __restrict__ q16,
    const float* __restrict__ kg, const float* __restrict__ kb,
    const float* __restrict__ s0p, const float* __restrict__ s1p,
    float* __restrict__ combine, float* __restrict__ dispatch)
{
    __shared__ float qs[16 * 1024];   // 64 KB
    int tid = threadIdx.x;
#pragma unroll
    for (int i = 0; i < 16; ++i)
        ((float4*)qs)[tid + i * 256] = ((const float4*)q16)[tid + i * 256];
    __syncthreads();

    int lane = tid & 63;
    int wv = tid >> 6;
    float inv0 = 1.0f / s0p[0];
    float inv1h = 0.5f / s1p[0];

    float4 kgr[4], kbr[4];
#pragma unroll
    for (int c = 0; c < 4; ++c) {
        kgr[c] = ((const float4*)kg)[c * 64 + lane];
        kbr[c] = ((const float4*)kb)[c * 64 + lane];
    }

    for (int i = 0; i < 8; ++i) {
        int tok = (blockIdx.x * 4 + wv) * 8 + i;       // 0..32767
        const float4* xr = (const float4*)(x + (size_t)tok * D_);
        float ks[16];
        float ss = 0.f;
#pragma unroll
        for (int c = 0; c < 4; ++c) {
            float4 v = xr[c * 64 + lane];
            float a0 = v.x * kgr[c].x + kbr[c].x;
            float a1 = v.y * kgr[c].y + kbr[c].y;
            float a2 = v.z * kgr[c].z + kbr[c].z;
            float a3 = v.w * kgr[c].w + kbr[c].w;
            ks[c * 4 + 0] = a0; ks[c * 4 + 1] = a1; ks[c * 4 + 2] = a2; ks[c * 4 + 3] = a3;
            ss += a0 * a0 + a1 * a1 + a2 * a2 + a3 * a3;
        }
#pragma unroll
        for (int m = 32; m; m >>= 1) ss += __shfl_xor(ss, m);
        float rn = 1.0f / (sqrtf(ss) + 1e-6f);

        float lg[16];
#pragma unroll
        for (int j = 0; j < 16; ++j) {
            float d = 0.f;
            const float4* qj = (const float4*)(qs + j * 1024);
#pragma unroll
            for (int c = 0; c < 4; ++c) {
                float4 q = qj[c * 64 + lane];
                d += ks[c * 4 + 0] * q.x + ks[c * 4 + 1] * q.y
                   + ks[c * 4 + 2] * q.z + ks[c * 4 + 3] * q.w;
            }
#pragma unroll
            for (int m = 32; m; m >>= 1) d += __shfl_xor(d, m);
            lg[j] = d * rn;
        }

        // dispatch: softmax over 8 core experts, per slot s (occ underflow = exact 0)
        float dsp[16];
#pragma unroll
        for (int s = 0; s < 2; ++s) {
            float a[8], m = -1e30f;
#pragma unroll
            for (int ee = 0; ee < 8; ++ee) { a[ee] = lg[2 * ee + s] * inv0; m = fmaxf(m, a[ee]); }
            float den = 0.f;
#pragma unroll
            for (int ee = 0; ee < 8; ++ee) { a[ee] = expf(a[ee] - m); den += a[ee]; }
            float r = 1.0f / den;
#pragma unroll
            for (int ee = 0; ee < 8; ++ee) dsp[2 * ee + s] = a[ee] * r;
        }

        // combine: exact 1.5-entmax over the 16 core slot logits
        float z[16], zmax = -1e30f;
#pragma unroll
        for (int j = 0; j < 16; ++j) { z[j] = lg[j] * inv1h; zmax = fmaxf(zmax, z[j]); }
#pragma unroll
        for (int j = 0; j < 16; ++j) z[j] -= zmax;
        float zsr[16];
#pragma unroll
        for (int j = 0; j < 16; ++j) zsr[j] = z[j];
        // odd-even transposition sort (descending), fully register-resident
#pragma unroll
        for (int r = 0; r < 16; ++r) {
#pragma unroll
            for (int jj = (r & 1); jj + 1 < 16; jj += 2) {
                float aa = zsr[jj], bb = zsr[jj + 1];
                zsr[jj] = fmaxf(aa, bb);
                zsr[jj + 1] = fminf(aa, bb);
            }
        }
        float cs = 0.f, css = 0.f, tau_star = 0.f;
#pragma unroll
        for (int kk = 1; kk <= 16; ++kk) {
            cs += zsr[kk - 1];
            css += zsr[kk - 1] * zsr[kk - 1];
            float fk = (float)kk;
            float mean = cs / fk, msq = css / fk;
            float ssv = fk * (msq - mean * mean);
            float delta = fmaxf((1.0f - ssv) / fk, 1e-12f);
            float tau = mean - sqrtf(delta);
            tau_star = (tau <= zsr[kk - 1]) ? tau : tau_star;  // predicate is prefix-true
        }
        float cmb[16];
#pragma unroll
        for (int j = 0; j < 16; ++j) { float t = fmaxf(z[j] - tau_star, 0.f); cmb[j] = t * t; }

        // write: lanes 0..15 -> combine row, lanes 16..31 -> dispatch row
        int lj = lane & 15;
        float cvv = 0.f, dvv = 0.f;
#pragma unroll
        for (int j = 0; j < 16; ++j) {
            cvv = (lj == j) ? cmb[j] : cvv;
            dvv = (lj == j) ? dsp[j] : dvv;
        }
        if (lane < 16)      combine[(size_t)tok * 16 + lj] = cvv;
        else if (lane < 32) dispatch[(size_t)tok * 16 + lj] = dvv;
    }
}

// ---------------------------------------------------------------------------
// K2b: partial slots. partial[b][nc][j][d] = sum_{n in chunk nc} disp[n][j]*x[b,n,d]
// grid (nc=16, dc=4, b=8); thread owns one d, 16 accumulators.
// ---------------------------------------------------------------------------
__global__ __launch_bounds__(256) void k_slots_partial(
    const float* __restrict__ x, const float* __restrict__ dispatch,
    float* __restrict__ partial)
{
    int nc = blockIdx.x, dc = blockIdx.y, b = blockIdx.z;
    int d = dc * 256 + threadIdx.x;
    const float* xb = x + (size_t)b * N_ * D_ + d;
    const float* db = dispatch + (size_t)b * N_ * 16;
    float acc[16];
#pragma unroll
    for (int j = 0; j < 16; ++j) acc[j] = 0.f;
    int n0 = nc * 256;
#pragma unroll 2
    for (int n = n0; n < n0 + 256; ++n) {
        float xv = xb[(size_t)n * D_];
        const float4* dp = (const float4*)(db + (size_t)n * 16);
        float4 q0 = dp[0], q1 = dp[1], q2 = dp[2], q3 = dp[3];
        acc[0]  += q0.x * xv; acc[1]  += q0.y * xv; acc[2]  += q0.z * xv; acc[3]  += q0.w * xv;
        acc[4]  += q1.x * xv; acc[5]  += q1.y * xv; acc[6]  += q1.z * xv; acc[7]  += q1.w * xv;
        acc[8]  += q2.x * xv; acc[9]  += q2.y * xv; acc[10] += q2.z * xv; acc[11] += q2.w * xv;
        acc[12] += q3.x * xv; acc[13] += q3.y * xv; acc[14] += q3.z * xv; acc[15] += q3.w * xv;
    }
#pragma unroll
    for (int j = 0; j < 16; ++j)
        partial[(((size_t)b * 16 + nc) * 16 + j) * 1024 + d] = acc[j];
}

// ---------------------------------------------------------------------------
// K2c: reduce partials -> slotsT[e][k][t]  (t = b*2+s; t-fast for scalar loads)
// ---------------------------------------------------------------------------
__global__ __launch_bounds__(256) void k_slots_reduce(
    const float* __restrict__ partial, float* __restrict__ slotsT)
{
    int idx = blockIdx.x * 256 + threadIdx.x;   // 0..131071
    int t = idx & 15;
    int k = (idx >> 4) & 1023;
    int e = idx >> 14;
    int b = t >> 1, s = t & 1;
    int j = e * 2 + s;
    const float* p = partial + (((size_t)b * 16) * 16 + j) * 1024 + k;
    float sum = 0.f;
#pragma unroll
    for (int nc = 0; nc < 16; ++nc) sum += p[(size_t)nc * 16 * 1024];
    slotsT[idx] = sum;
}

// ---------------------------------------------------------------------------
// D1: h = gelu(slots @ w1 + b1), stored t-fast: hT[e][h][t]
// grid (colchunk=64, e=8), 512 threads = 64 cols x 8 k-splits of 128.
// ---------------------------------------------------------------------------
__global__ __launch_bounds__(512) void k_mlp1(
    const float* __restrict__ w1, const float* __restrict__ b1,
    const float* __restrict__ slotsT, float* __restrict__ hT)
{
    int e = blockIdx.y;
    int col0 = blockIdx.x * 64;
    int tid = threadIdx.x;
    int cl = tid & 63;
    int p = tid >> 6;                 // 0..7
    const float* wp = w1 + ((size_t)e * 1024 + p * 128) * 4096 + col0 + cl;
    const float4* sp = (const float4*)(slotsT + ((size_t)e * 1024 + p * 128) * 16);
    float acc[16];
#pragma unroll
    for (int t = 0; t < 16; ++t) acc[t] = 0.f;
#pragma unroll 2
    for (int k = 0; k < 128; ++k) {
        float w = wp[(size_t)k * 4096];
        float4 a = sp[k * 4 + 0], bq = sp[k * 4 + 1], cq = sp[k * 4 + 2], dq = sp[k * 4 + 3];
        acc[0]  += w * a.x;  acc[1]  += w * a.y;  acc[2]  += w * a.z;  acc[3]  += w * a.w;
        acc[4]  += w * bq.x; acc[5]  += w * bq.y; acc[6]  += w * bq.z; acc[7]  += w * bq.w;
        acc[8]  += w * cq.x; acc[9]  += w * cq.y; acc[10] += w * cq.z; acc[11] += w * cq.w;
        acc[12] += w * dq.x; acc[13] += w * dq.y; acc[14] += w * dq.z; acc[15] += w * dq.w;
    }
    __shared__ float red[8 * 64 * 17];
#pragma unroll
    for (int t = 0; t < 16; ++t) red[(p * 64 + cl) * 17 + t] = acc[t];
    __syncthreads();
#pragma unroll
    for (int i = 0; i < 2; ++i) {
        int oi = tid + 512 * i;       // 0..1023; t-fast => contiguous hT writes
        int t = oi & 15, c = oi >> 4;
        float v = 0.f;
#pragma unroll
        for (int pp = 0; pp < 8; ++pp) v += red[(pp * 64 + c) * 17 + t];
        v += b1[(size_t)e * 4096 + col0 + c];
        v = 0.5f * v * (1.0f + erff(v * 0.70710678118654752f));   // exact GELU
        hT[((size_t)e * 4096 + col0 + c) * 16 + t] = v;
    }
}

// ---------------------------------------------------------------------------
// D2: core_out = h @ w2 + b2, stored co[b][j][d] (j = e*2+s)
// grid (colchunk=32, e=8), 512 threads = 32 cols x 16 k-splits of 256.
// ---------------------------------------------------------------------------
__global__ __launch_bounds__(512) void k_mlp2(
    const float* __restrict__ w2, const float* __restrict__ b2,
    const float* __restrict__ hT, float* __restrict__ co)
{
    int e = blockIdx.y;
    int col0 = blockIdx.x * 32;
    int tid = threadIdx.x;
    int cl = tid & 31;
    int p = tid >> 5;                 // 0..15
    const float* wp = w2 + ((size_t)e * 4096 + p * 256) * 1024 + col0 + cl;
    const float4* hp = (const float4*)(hT + ((size_t)e * 4096 + p * 256) * 16);
    float acc[16];
#pragma unroll
    for (int t = 0; t < 16; ++t) acc[t] = 0.f;
#pragma unroll 2
    for (int k = 0; k < 256; ++k) {
        float w = wp[(size_t)k * 1024];
        float4 a = hp[k * 4 + 0], bq = hp[k * 4 + 1], cq = hp[k * 4 + 2], dq = hp[k * 4 + 3];
        acc[0]  += w * a.x;  acc[1]  += w * a.y;  acc[2]  += w * a.z;  acc[3]  += w * a.w;
        acc[4]  += w * bq.x; acc[5]  += w * bq.y; acc[6]  += w * bq.z; acc[7]  += w * bq.w;
        acc[8]  += w * cq.x; acc[9]  += w * cq.y; acc[10] += w * cq.z; acc[11] += w * cq.w;
        acc[12] += w * dq.x; acc[13] += w * dq.y; acc[14] += w * dq.z; acc[15] += w * dq.w;
    }
    __shared__ float red[16 * 32 * 17];
#pragma unroll
    for (int t = 0; t < 16; ++t) red[(p * 32 + cl) * 17 + t] = acc[t];
    __syncthreads();
    // 512 outputs, 512 threads, col-fast mapping for ~coalesced writes
    int c = tid & 31, t = tid >> 5;
    float v = 0.f;
#pragma unroll
    for (int pp = 0; pp < 16; ++pp) v += red[(pp * 32 + c) * 17 + t];
    v += b2[(size_t)e * 1024 + col0 + c];
    int bq2 = t >> 1, s = t & 1;
    co[(((size_t)bq2 * 16) + e * 2 + s) * 1024 + col0 + c] = v;
}

// ---------------------------------------------------------------------------
// KE: out[b,n,:] = sum_j combine[b,n,j] * co[b][j][:]
// Register-stage co[b] (16 x float4 per thread). grid (tile=64, b=8).
// ---------------------------------------------------------------------------
__global__ __launch_bounds__(256) void k_out(
    const float* __restrict__ co, const float* __restrict__ combine,
    float* __restrict__ out)
{
    int b = blockIdx.y, tile = blockIdx.x;     // 64 tokens per tile
    int tid = threadIdx.x;
    float4 cv[16];
#pragma unroll
    for (int j = 0; j < 16; ++j)
        cv[j] = ((const float4*)(co + ((size_t)b * 16 + j) * 1024))[tid];
    const float* cb = combine + ((size_t)b * N_ + tile * 64) * 16;
    float4* ob = (float4*)(out + ((size_t)b * N_ + tile * 64) * 1024) + tid;
    for (int it = 0; it < 64; ++it) {
        const float* cm = cb + it * 16;
        float4 acc; acc.x = 0.f; acc.y = 0.f; acc.z = 0.f; acc.w = 0.f;
#pragma unroll
        for (int j = 0; j < 16; ++j) {
            float wj = cm[j];
            acc.x += wj * cv[j].x; acc.y += wj * cv[j].y;
            acc.z += wj * cv[j].z; acc.w += wj * cv[j].w;
        }
        ob[(size_t)it * 256] = acc;
    }
}

// ---------------------------------------------------------------------------
extern "C" void kernel_launch(void* const* d_in, const int* in_sizes, int n_in,
                              void* d_out, int out_size, void* d_ws, size_t ws_size,
                              hipStream_t stream)
{
    const float* x   = (const float*)d_in[0];
    // d_in[1] attn_weight: unused by the reference
    const float* phi = (const float*)d_in[2];
    const float* kg  = (const float*)d_in[3];
    const float* kb  = (const float*)d_in[4];
    const float* qg  = (const float*)d_in[5];
    const float* qb  = (const float*)d_in[6];
    const float* lng = (const float*)d_in[7];
    const float* lnb = (const float*)d_in[8];
    const float* s0  = (const float*)d_in[9];
    const float* s1  = (const float*)d_in[10];
    const float* w1  = (const float*)d_in[11];
    const float* b1  = (const float*)d_in[12];
    const float* w2  = (const float*)d_in[13];
    const float* b2  = (const float*)d_in[14];
    // d_in[15..18] occ weights: provably dead (exact-zero combine/dispatch)

    float* out = (float*)d_out;
    float* ws  = (float*)d_ws;

    float* q16      = ws;                       // 16384 floats
    float* combine  = q16 + 16384;              // 524288
    float* dispatch = combine + 524288;         // 524288
    float* partial  = dispatch + 524288;        // 2097152 (8*16*16*1024)
    float* slotsT   = partial + 2097152;        // 131072
    float* hT       = slotsT + 131072;          // 524288
    float* co       = hT + 524288;              // 131072

    k_q16          <<<dim3(16),        dim3(64),  0, stream>>>(phi, qg, qb, lng, lnb, q16);
    k_route        <<<dim3(1024),      dim3(256), 0, stream>>>(x, q16, kg, kb, s0, s1, combine, dispatch);
    k_slots_partial<<<dim3(16, 4, 8),  dim3(256), 0, stream>>>(x, dispatch, partial);
    k_slots_reduce <<<dim3(512),       dim3(256), 0, stream>>>(partial, slotsT);
    k_mlp1         <<<dim3(64, 8),     dim3(512), 0, stream>>>(w1, b1, slotsT, hT);
    k_mlp2         <<<dim3(32, 8),     dim3(512), 0, stream>>>(w2, b2, hT, co);
    k_out          <<<dim3(64, 8),     dim3(256), 0, stream>>>(co, combine, out);
}